// Round 2
// baseline (1562.275 us; speedup 1.0000x reference)
//
#include <hip/hip_runtime.h>
#include <math.h>

#define DIM   1024
#define HID   2048
#define NEXP  8
#define MTOK  16384      // 4*4096 tokens
#define NSLOT 32768      // MTOK * top2

// header layout (ints) at ws+0
#define H_COUNT 0        // counts[8]
#define H_OFFS  8        // offsets[9]
#define H_CUR   24       // cursors[8]
#define H_NWORK 32       // n_work
#define H_WL    64       // worklist[<=263], (e<<16)|tile

typedef unsigned short ushort_t;
typedef __bf16 bf16x8 __attribute__((ext_vector_type(8)));
typedef float floatx4 __attribute__((ext_vector_type(4)));

__device__ __forceinline__ unsigned short f2bf(float f) {
  union { float f; unsigned int i; } z; z.f = f;
  unsigned int r = z.i + 0x7fffu + ((z.i >> 16) & 1u);
  return (unsigned short)(r >> 16);
}

__global__ void k0_init(int* hdr) {
  int t = threadIdx.x;
  if (t < 64) hdr[t] = 0;
}

// fp32 -> bf16 conversion (grid-stride over float4s)
__global__ __launch_bounds__(256) void kconv(
    const float* __restrict__ src, ushort_t* __restrict__ dst, int n4)
{
  int i = blockIdx.x * 256 + threadIdx.x;
  int stride = gridDim.x * 256;
  for (; i < n4; i += stride) {
    float4 v = ((const float4*)src)[i];
    ushort4 o; o.x = f2bf(v.x); o.y = f2bf(v.y); o.z = f2bf(v.z); o.w = f2bf(v.w);
    ((ushort4*)dst)[i] = o;
  }
}

// RMSNorm + residual-copy + router + top2 + softmax. One block (256 thr)/token.
__global__ __launch_bounds__(256) void k1_norm_router(
    const float* __restrict__ x, const float* __restrict__ scale,
    const float* __restrict__ wr, ushort_t* __restrict__ xn,
    float* __restrict__ out, int* __restrict__ ids, float* __restrict__ wts,
    int* __restrict__ hdr)
{
  int token = blockIdx.x, t = threadIdx.x;
  int lane = t & 63, wid = t >> 6;

  float4 xv = ((const float4*)(x + (size_t)token * DIM))[t];
  ((float4*)(out + (size_t)token * DIM))[t] = xv;   // residual
  double ss = (double)xv.x*xv.x + (double)xv.y*xv.y
            + (double)xv.z*xv.z + (double)xv.w*xv.w;
  #pragma unroll
  for (int o = 32; o; o >>= 1) ss += __shfl_down(ss, o, 64);

  __shared__ double sred[4];
  __shared__ float sbc;
  if (lane == 0) sred[wid] = ss;
  __syncthreads();
  if (t == 0) {
    double ms = (sred[0] + sred[1] + sred[2] + sred[3]) * (1.0 / (double)DIM);
    sbc = (float)(1.0 / sqrt(ms + 1e-6));
  }
  __syncthreads();
  float s = sbc;
  float4 sv = ((const float4*)scale)[t];
  float n0f = xv.x * s * sv.x, n1f = xv.y * s * sv.y;
  float n2f = xv.z * s * sv.z, n3f = xv.w * s * sv.w;
  ushort4 xo; xo.x = f2bf(n0f); xo.y = f2bf(n1f); xo.z = f2bf(n2f); xo.w = f2bf(n3f);
  ((ushort4*)(xn + (size_t)token * DIM))[t] = xo;

  // router scores from fp32 xn, fp64 accumulation
  double p[NEXP];
  #pragma unroll
  for (int e = 0; e < NEXP; e++) {
    float4 wv = ((const float4*)(wr + e * DIM))[t];
    p[e] = (double)n0f * wv.x + (double)n1f * wv.y
         + (double)n2f * wv.z + (double)n3f * wv.w;
  }
  #pragma unroll
  for (int e = 0; e < NEXP; e++) {
    double v = p[e];
    #pragma unroll
    for (int o = 32; o; o >>= 1) v += __shfl_down(v, o, 64);
    p[e] = v;
  }
  __shared__ double pr[4][NEXP];
  if (lane == 0) {
    #pragma unroll
    for (int e = 0; e < NEXP; e++) pr[wid][e] = p[e];
  }
  __syncthreads();
  if (t == 0) {
    double sc[NEXP];
    #pragma unroll
    for (int e = 0; e < NEXP; e++) sc[e] = pr[0][e] + pr[1][e] + pr[2][e] + pr[3][e];
    int e0 = 0;
    for (int e = 1; e < NEXP; e++) if (sc[e] > sc[e0]) e0 = e;        // ties: lowest idx
    int e1 = (e0 == 0) ? 1 : 0;
    for (int e = 0; e < NEXP; e++) if (e != e0 && sc[e] > sc[e1]) e1 = e;
    double d = exp(sc[e1] - sc[e0]);                                  // <= 1
    float w0 = (float)(1.0 / (1.0 + d));
    float w1 = (float)(d / (1.0 + d));
    ids[2 * token] = e0; ids[2 * token + 1] = e1;
    wts[2 * token] = w0; wts[2 * token + 1] = w1;
    atomicAdd(&hdr[H_COUNT + e0], 1);
    atomicAdd(&hdr[H_COUNT + e1], 1);
  }
}

// serial scan + worklist (tiny, deterministic work)
__global__ void k2_scan(int* hdr) {
  if (threadIdx.x == 0 && blockIdx.x == 0) {
    int off = 0;
    for (int e = 0; e < NEXP; e++) { hdr[H_OFFS + e] = off; off += hdr[H_COUNT + e]; }
    hdr[H_OFFS + NEXP] = off;
    int n = 0;
    for (int e = 0; e < NEXP; e++) {
      int tiles = (hdr[H_COUNT + e] + 127) >> 7;
      for (int i = 0; i < tiles; i++) hdr[H_WL + n++] = (e << 16) | i;
    }
    hdr[H_NWORK] = n;
  }
}

__global__ __launch_bounds__(256) void k3_scatter(
    const int* __restrict__ ids, int* __restrict__ hdr, int* __restrict__ perm)
{
  int s = blockIdx.x * 256 + threadIdx.x;
  if (s < NSLOT) {
    int e = ids[s];
    int pos = atomicAdd(&hdr[H_CUR + e], 1);
    perm[hdr[H_OFFS + e] + pos] = s;
  }
}

// grouped GEMM: up + SwiGLU. Tile 128 rows x (64 u-cols + 64 gate-cols), K=1024.
__global__ __launch_bounds__(256) void k4_up(
    const ushort_t* __restrict__ xn, const ushort_t* __restrict__ wup,
    const int* __restrict__ hdr, const int* __restrict__ perm,
    ushort_t* __restrict__ h)
{
  if ((int)blockIdx.x >= hdr[H_NWORK]) return;
  int wl = hdr[H_WL + blockIdx.x];
  int e = wl >> 16, tile = wl & 0xffff;
  int gs = hdr[H_OFFS + e];
  int row0 = gs + (tile << 7);
  int nrows = hdr[H_OFFS + e + 1] - row0; if (nrows > 128) nrows = 128;
  int n0 = blockIdx.y << 6;   // h-col base (0..2047 step 64)

  __shared__ __align__(16) ushort_t As[4096];  // [128 rows][32 k]
  __shared__ __align__(16) ushort_t Bs[4096];  // [128 cols][32 k]
  __shared__ int rowslot[128];

  int t = threadIdx.x;
  if (t < 128) rowslot[t] = (t < nrows) ? perm[row0 + t] : -1;

  int rA = t >> 2, seg = t & 3;
  int tok0 = perm[row0 + (rA      < nrows ? rA      : 0)] >> 1;
  int tok1 = perm[row0 + (rA + 64 < nrows ? rA + 64 : 0)] >> 1;
  const ushort_t* ap0 = xn + (size_t)tok0 * DIM + seg * 8;
  const ushort_t* ap1 = xn + (size_t)tok1 * DIM + seg * 8;
  const ushort_t* wbase = wup + (size_t)e * 4096 * DIM;
  const ushort_t* bp0 = wbase + (size_t)(n0 + rA) * DIM + seg * 8;          // u rows
  const ushort_t* bp1 = wbase + (size_t)(2048 + n0 + rA) * DIM + seg * 8;   // gate rows

  floatx4 acc[16];
  #pragma unroll
  for (int i = 0; i < 16; i++) acc[i] = (floatx4){0.f, 0.f, 0.f, 0.f};

  int lane = t & 63, wave = t >> 6;
  int quad = lane >> 4, l15 = lane & 15;
  int aoff0 = ((wave * 32      + l15) << 5) + (quad << 3);
  int aoff1 = ((wave * 32 + 16 + l15) << 5) + (quad << 3);

  for (int kb = 0; kb < DIM / 32; ++kb) {
    uint4 a0 = *(const uint4*)ap0;  ap0 += 32;
    uint4 a1 = *(const uint4*)ap1;  ap1 += 32;
    uint4 b0 = *(const uint4*)bp0;  bp0 += 32;
    uint4 b1 = *(const uint4*)bp1;  bp1 += 32;
    __syncthreads();
    *(uint4*)(As + t * 8)        = a0;
    *(uint4*)(As + 2048 + t * 8) = a1;
    *(uint4*)(Bs + t * 8)        = b0;
    *(uint4*)(Bs + 2048 + t * 8) = b1;
    __syncthreads();
    bf16x8 af0 = *(const bf16x8*)(As + aoff0);
    bf16x8 af1 = *(const bf16x8*)(As + aoff1);
    #pragma unroll
    for (int ct = 0; ct < 8; ++ct) {
      bf16x8 bfr = *(const bf16x8*)(Bs + ((ct * 16 + l15) << 5) + (quad << 3));
      acc[ct]     = __builtin_amdgcn_mfma_f32_16x16x32_bf16(af0, bfr, acc[ct],     0, 0, 0);
      acc[8 + ct] = __builtin_amdgcn_mfma_f32_16x16x32_bf16(af1, bfr, acc[8 + ct], 0, 0, 0);
    }
  }

  // SwiGLU: col-tiles 0..3 = u, 4..7 = gate (same lane holds the matching pair)
  #pragma unroll
  for (int rt = 0; rt < 2; ++rt)
  #pragma unroll
  for (int ct = 0; ct < 4; ++ct) {
    floatx4 u = acc[rt * 8 + ct];
    floatx4 g = acc[rt * 8 + ct + 4];
    #pragma unroll
    for (int j = 0; j < 4; ++j) {
      int r = wave * 32 + rt * 16 + quad * 4 + j;
      int slot = rowslot[r];
      if (slot >= 0) {
        float gv = g[j];
        float hv = u[j] * (gv / (1.0f + expf(-gv)));
        h[(size_t)slot * HID + n0 + ct * 16 + l15] = f2bf(hv);
      }
    }
  }
}

// grouped GEMM: down, weighted by softmax weight, atomically added into out.
// Tile 128 rows x 128 cols, K=2048.
__global__ __launch_bounds__(256) void k5_down(
    const ushort_t* __restrict__ h, const ushort_t* __restrict__ wdn,
    const int* __restrict__ hdr, const int* __restrict__ perm,
    const float* __restrict__ wts, float* __restrict__ out)
{
  if ((int)blockIdx.x >= hdr[H_NWORK]) return;
  int wl = hdr[H_WL + blockIdx.x];
  int e = wl >> 16, tile = wl & 0xffff;
  int gs = hdr[H_OFFS + e];
  int row0 = gs + (tile << 7);
  int nrows = hdr[H_OFFS + e + 1] - row0; if (nrows > 128) nrows = 128;
  int n0 = blockIdx.y << 7;   // out-col base (0..1023 step 128)

  __shared__ __align__(16) ushort_t As[4096];
  __shared__ __align__(16) ushort_t Bs[4096];
  __shared__ int rowslot[128];
  __shared__ float roww[128];

  int t = threadIdx.x;
  if (t < 128) {
    int sl = (t < nrows) ? perm[row0 + t] : -1;
    rowslot[t] = sl;
    roww[t] = (sl >= 0) ? wts[sl] : 0.f;
  }

  int rA = t >> 2, seg = t & 3;
  int sl0 = perm[row0 + (rA      < nrows ? rA      : 0)];
  int sl1 = perm[row0 + (rA + 64 < nrows ? rA + 64 : 0)];
  const ushort_t* ap0 = h + (size_t)sl0 * HID + seg * 8;
  const ushort_t* ap1 = h + (size_t)sl1 * HID + seg * 8;
  const ushort_t* wbase = wdn + (size_t)e * DIM * HID;
  const ushort_t* bp0 = wbase + (size_t)(n0 + rA) * HID + seg * 8;
  const ushort_t* bp1 = wbase + (size_t)(n0 + 64 + rA) * HID + seg * 8;

  floatx4 acc[16];
  #pragma unroll
  for (int i = 0; i < 16; i++) acc[i] = (floatx4){0.f, 0.f, 0.f, 0.f};

  int lane = t & 63, wave = t >> 6;
  int quad = lane >> 4, l15 = lane & 15;
  int aoff0 = ((wave * 32      + l15) << 5) + (quad << 3);
  int aoff1 = ((wave * 32 + 16 + l15) << 5) + (quad << 3);

  for (int kb = 0; kb < HID / 32; ++kb) {
    uint4 a0 = *(const uint4*)ap0;  ap0 += 32;
    uint4 a1 = *(const uint4*)ap1;  ap1 += 32;
    uint4 b0 = *(const uint4*)bp0;  bp0 += 32;
    uint4 b1 = *(const uint4*)bp1;  bp1 += 32;
    __syncthreads();
    *(uint4*)(As + t * 8)        = a0;
    *(uint4*)(As + 2048 + t * 8) = a1;
    *(uint4*)(Bs + t * 8)        = b0;
    *(uint4*)(Bs + 2048 + t * 8) = b1;
    __syncthreads();
    bf16x8 af0 = *(const bf16x8*)(As + aoff0);
    bf16x8 af1 = *(const bf16x8*)(As + aoff1);
    #pragma unroll
    for (int ct = 0; ct < 8; ++ct) {
      bf16x8 bfr = *(const bf16x8*)(Bs + ((ct * 16 + l15) << 5) + (quad << 3));
      acc[ct]     = __builtin_amdgcn_mfma_f32_16x16x32_bf16(af0, bfr, acc[ct],     0, 0, 0);
      acc[8 + ct] = __builtin_amdgcn_mfma_f32_16x16x32_bf16(af1, bfr, acc[8 + ct], 0, 0, 0);
    }
  }

  #pragma unroll
  for (int rt = 0; rt < 2; ++rt)
  #pragma unroll
  for (int ct = 0; ct < 8; ++ct) {
    floatx4 d = acc[rt * 8 + ct];
    #pragma unroll
    for (int j = 0; j < 4; ++j) {
      int r = wave * 32 + rt * 16 + quad * 4 + j;
      int slot = rowslot[r];
      if (slot >= 0) {
        int tok = slot >> 1;
        atomicAdd(&out[(size_t)tok * DIM + n0 + ct * 16 + l15], d[j] * roww[r]);
      }
    }
  }
}

extern "C" void kernel_launch(void* const* d_in, const int* in_sizes, int n_in,
                              void* d_out, int out_size, void* d_ws, size_t ws_size,
                              hipStream_t stream)
{
  const float* x   = (const float*)d_in[0];
  const float* sc  = (const float*)d_in[1];
  const float* wr  = (const float*)d_in[2];
  const float* wup = (const float*)d_in[3];
  const float* wdn = (const float*)d_in[4];
  float* out = (float*)d_out;

  char* ws = (char*)d_ws;
  int*      hdr  = (int*)ws;                                    // 16 KB header
  int*      ids  = (int*)(ws + 16384);                          // [NSLOT]
  float*    wts  = (float*)(ws + 147456);                       // [NSLOT]
  int*      perm = (int*)(ws + 278528);                         // [NSLOT]
  ushort_t* xn   = (ushort_t*)(ws + 409600);                    // [MTOK*DIM] bf16, 32MB
  ushort_t* h    = (ushort_t*)(ws + 33964032ull);               // [NSLOT*HID] bf16, 128MB
  ushort_t* wupb = (ushort_t*)(ws + 168181760ull);              // [8*4096*1024] bf16, 64MB
  ushort_t* wdnb = (ushort_t*)(ws + 168181760ull);              // [8*1024*2048] bf16, 32MB
  // wdnb overlaps wupb: converted AFTER k4 (wupb dead by then). Peak ws ~224 MiB.

  k0_init<<<1, 64, 0, stream>>>(hdr);
  kconv<<<4096, 256, 0, stream>>>(wup, wupb, NEXP * 2 * HID * DIM / 4);
  k1_norm_router<<<MTOK, 256, 0, stream>>>(x, sc, wr, xn, out, ids, wts, hdr);
  k2_scan<<<1, 64, 0, stream>>>(hdr);
  k3_scatter<<<NSLOT / 256, 256, 0, stream>>>(ids, hdr, perm);
  k4_up<<<dim3(263, 32), 256, 0, stream>>>(xn, wupb, hdr, perm, h);
  kconv<<<4096, 256, 0, stream>>>(wdn, wdnb, NEXP * DIM * HID / 4);
  k5_down<<<dim3(263, 8), 256, 0, stream>>>(h, wdnb, hdr, perm, wts, out);
}

// Round 3
// 1410.063 us; speedup vs baseline: 1.1079x; 1.1079x over previous
//
#include <hip/hip_runtime.h>
#include <math.h>

#define DIM   1024
#define HID   2048
#define NEXP  8
#define MTOK  16384      // 4*4096 tokens
#define NSLOT 32768      // MTOK * top2

// header layout (ints) at ws+0
#define H_COUNT 0        // counts[8]
#define H_OFFS  8        // offsets[9]
#define H_CUR   24       // cursors[8]
#define H_NWORK 32       // n_work
#define H_WL    64       // worklist[<=263], (e<<16)|tile

typedef unsigned short ushort_t;
typedef unsigned int u32;
typedef __bf16 bf16x8 __attribute__((ext_vector_type(8)));
typedef float floatx4 __attribute__((ext_vector_type(4)));

__device__ __forceinline__ unsigned short f2bf(float f) {
  union { float f; unsigned int i; } z; z.f = f;
  unsigned int r = z.i + 0x7fffu + ((z.i >> 16) & 1u);
  return (unsigned short)(r >> 16);
}

// async global->LDS, 16B per lane. lds dest must be the wave-uniform base;
// HW scatters lane i to base + i*16.
__device__ __forceinline__ void gld16(const ushort_t* g, ushort_t* l) {
  __builtin_amdgcn_global_load_lds(
      (const __attribute__((address_space(1))) u32*)g,
      (__attribute__((address_space(3))) u32*)l, 16, 0, 0);
}

__global__ void k0_init(int* hdr) {
  int t = threadIdx.x;
  if (t < 64) hdr[t] = 0;
}

// fp32 -> bf16 conversion (grid-stride over float4s)
__global__ __launch_bounds__(256) void kconv(
    const float* __restrict__ src, ushort_t* __restrict__ dst, int n4)
{
  int i = blockIdx.x * 256 + threadIdx.x;
  int stride = gridDim.x * 256;
  for (; i < n4; i += stride) {
    float4 v = ((const float4*)src)[i];
    ushort4 o; o.x = f2bf(v.x); o.y = f2bf(v.y); o.z = f2bf(v.z); o.w = f2bf(v.w);
    ((ushort4*)dst)[i] = o;
  }
}

// RMSNorm + router + top2 + softmax. One block (256 thr)/token.
__global__ __launch_bounds__(256) void k1_norm_router(
    const float* __restrict__ x, const float* __restrict__ scale,
    const float* __restrict__ wr, ushort_t* __restrict__ xn,
    int* __restrict__ ids, float* __restrict__ wts, int* __restrict__ hdr)
{
  int token = blockIdx.x, t = threadIdx.x;
  int lane = t & 63, wid = t >> 6;

  float4 xv = ((const float4*)(x + (size_t)token * DIM))[t];
  double ss = (double)xv.x*xv.x + (double)xv.y*xv.y
            + (double)xv.z*xv.z + (double)xv.w*xv.w;
  #pragma unroll
  for (int o = 32; o; o >>= 1) ss += __shfl_down(ss, o, 64);

  __shared__ double sred[4];
  __shared__ float sbc;
  if (lane == 0) sred[wid] = ss;
  __syncthreads();
  if (t == 0) {
    double ms = (sred[0] + sred[1] + sred[2] + sred[3]) * (1.0 / (double)DIM);
    sbc = (float)(1.0 / sqrt(ms + 1e-6));
  }
  __syncthreads();
  float s = sbc;
  float4 sv = ((const float4*)scale)[t];
  float n0f = xv.x * s * sv.x, n1f = xv.y * s * sv.y;
  float n2f = xv.z * s * sv.z, n3f = xv.w * s * sv.w;
  ushort4 xo; xo.x = f2bf(n0f); xo.y = f2bf(n1f); xo.z = f2bf(n2f); xo.w = f2bf(n3f);
  ((ushort4*)(xn + (size_t)token * DIM))[t] = xo;

  // router scores from fp32 xn, fp64 accumulation
  double p[NEXP];
  #pragma unroll
  for (int e = 0; e < NEXP; e++) {
    float4 wv = ((const float4*)(wr + e * DIM))[t];
    p[e] = (double)n0f * wv.x + (double)n1f * wv.y
         + (double)n2f * wv.z + (double)n3f * wv.w;
  }
  #pragma unroll
  for (int e = 0; e < NEXP; e++) {
    double v = p[e];
    #pragma unroll
    for (int o = 32; o; o >>= 1) v += __shfl_down(v, o, 64);
    p[e] = v;
  }
  __shared__ double pr[4][NEXP];
  if (lane == 0) {
    #pragma unroll
    for (int e = 0; e < NEXP; e++) pr[wid][e] = p[e];
  }
  __syncthreads();
  if (t == 0) {
    double sc[NEXP];
    #pragma unroll
    for (int e = 0; e < NEXP; e++) sc[e] = pr[0][e] + pr[1][e] + pr[2][e] + pr[3][e];
    int e0 = 0;
    for (int e = 1; e < NEXP; e++) if (sc[e] > sc[e0]) e0 = e;        // ties: lowest idx
    int e1 = (e0 == 0) ? 1 : 0;
    for (int e = 0; e < NEXP; e++) if (e != e0 && sc[e] > sc[e1]) e1 = e;
    double d = exp(sc[e1] - sc[e0]);                                  // <= 1
    float w0 = (float)(1.0 / (1.0 + d));
    float w1 = (float)(d / (1.0 + d));
    ids[2 * token] = e0; ids[2 * token + 1] = e1;
    wts[2 * token] = w0; wts[2 * token + 1] = w1;
    atomicAdd(&hdr[H_COUNT + e0], 1);
    atomicAdd(&hdr[H_COUNT + e1], 1);
  }
}

// serial scan + worklist (tiny, deterministic work)
__global__ void k2_scan(int* hdr) {
  if (threadIdx.x == 0 && blockIdx.x == 0) {
    int off = 0;
    for (int e = 0; e < NEXP; e++) { hdr[H_OFFS + e] = off; off += hdr[H_COUNT + e]; }
    hdr[H_OFFS + NEXP] = off;
    int n = 0;
    for (int e = 0; e < NEXP; e++) {
      int tiles = (hdr[H_COUNT + e] + 127) >> 7;
      for (int i = 0; i < tiles; i++) hdr[H_WL + n++] = (e << 16) | i;
    }
    hdr[H_NWORK] = n;
  }
}

__global__ __launch_bounds__(256) void k3_scatter(
    const int* __restrict__ ids, int* __restrict__ hdr, int* __restrict__ perm)
{
  int s = blockIdx.x * 256 + threadIdx.x;
  if (s < NSLOT) {
    int e = ids[s];
    int pos = atomicAdd(&hdr[H_CUR + e], 1);
    perm[hdr[H_OFFS + e] + pos] = s;
  }
}

// grouped GEMM: up + SwiGLU. Tile 128 rows x (64 u-cols + 64 gate-cols), K=1024.
// grid (32 colchunks, 263 tiles): colchunk%8 pins B-chunk to one XCD's L2.
__global__ __launch_bounds__(256) void k4_up(
    const ushort_t* __restrict__ xn, const ushort_t* __restrict__ wup,
    const int* __restrict__ hdr, const int* __restrict__ perm,
    ushort_t* __restrict__ h)
{
  if ((int)blockIdx.y >= hdr[H_NWORK]) return;
  int wl = hdr[H_WL + blockIdx.y];
  int e = wl >> 16, tile = wl & 0xffff;
  int gs = hdr[H_OFFS + e];
  int row0 = gs + (tile << 7);
  int nrows = hdr[H_OFFS + e + 1] - row0; if (nrows > 128) nrows = 128;
  int n0 = blockIdx.x << 6;   // h-col base (0..2047 step 64)

  __shared__ __align__(16) ushort_t As[4096];  // [128 rows][32 k]
  __shared__ __align__(16) ushort_t Bs[4096];  // [128 cols][32 k]
  __shared__ int rowslot[128];

  int t = threadIdx.x;
  if (t < 128) rowslot[t] = (t < nrows) ? perm[row0 + t] : -1;

  int lane = t & 63, wave = t >> 6;
  int r16 = lane >> 2, seg = lane & 3;
  int rowA0 = wave * 16 + r16;        // staged row, issue 0 (0..63)
  int rowA1 = 64 + rowA0;             // issue 1 (64..127)

  int tok0 = perm[row0 + (rowA0 < nrows ? rowA0 : 0)] >> 1;
  int tok1 = perm[row0 + (rowA1 < nrows ? rowA1 : 0)] >> 1;
  const ushort_t* ap0 = xn + (size_t)tok0 * DIM + seg * 8;
  const ushort_t* ap1 = xn + (size_t)tok1 * DIM + seg * 8;
  const ushort_t* wbase = wup + (size_t)e * 4096 * DIM;
  const ushort_t* bp0 = wbase + (size_t)(n0 + rowA0) * DIM + seg * 8;        // u rows
  const ushort_t* bp1 = wbase + (size_t)(2048 + n0 + rowA0) * DIM + seg * 8; // gate rows

  ushort_t* lA0 = As + wave * 512;
  ushort_t* lA1 = As + 2048 + wave * 512;
  ushort_t* lB0 = Bs + wave * 512;
  ushort_t* lB1 = Bs + 2048 + wave * 512;

  floatx4 acc[16];
  #pragma unroll
  for (int i = 0; i < 16; i++) acc[i] = (floatx4){0.f, 0.f, 0.f, 0.f};

  int quad = lane >> 4, l15 = lane & 15;
  int aoff0 = ((wave * 32      + l15) << 5) + (quad << 3);
  int aoff1 = ((wave * 32 + 16 + l15) << 5) + (quad << 3);

  for (int kb = 0; kb < DIM / 32; ++kb) {
    gld16(ap0, lA0); gld16(ap1, lA1); gld16(bp0, lB0); gld16(bp1, lB1);
    ap0 += 32; ap1 += 32; bp0 += 32; bp1 += 32;
    __syncthreads();   // drains vmcnt(0): DMA data visible to all
    bf16x8 af0 = *(const bf16x8*)(As + aoff0);
    bf16x8 af1 = *(const bf16x8*)(As + aoff1);
    #pragma unroll
    for (int ct = 0; ct < 8; ++ct) {
      bf16x8 bfr = *(const bf16x8*)(Bs + ((ct * 16 + l15) << 5) + (quad << 3));
      acc[ct]     = __builtin_amdgcn_mfma_f32_16x16x32_bf16(af0, bfr, acc[ct],     0, 0, 0);
      acc[8 + ct] = __builtin_amdgcn_mfma_f32_16x16x32_bf16(af1, bfr, acc[8 + ct], 0, 0, 0);
    }
    __syncthreads();   // reads done before next iter's DMA overwrites
  }

  // SwiGLU: col-tiles 0..3 = u, 4..7 = gate (same lane holds the matching pair)
  #pragma unroll
  for (int rt = 0; rt < 2; ++rt)
  #pragma unroll
  for (int ct = 0; ct < 4; ++ct) {
    floatx4 u = acc[rt * 8 + ct];
    floatx4 g = acc[rt * 8 + ct + 4];
    #pragma unroll
    for (int j = 0; j < 4; ++j) {
      int r = wave * 32 + rt * 16 + quad * 4 + j;
      int slot = rowslot[r];
      if (slot >= 0) {
        float gv = g[j];
        float hv = u[j] * (gv / (1.0f + expf(-gv)));
        h[(size_t)slot * HID + n0 + ct * 16 + l15] = f2bf(hv);
      }
    }
  }
}

// grouped GEMM: down, weighted by softmax weight -> bf16 dwn. K=2048.
// grid (8 colchunks, 263 tiles): colchunk == XCD -> B stays in its L2.
__global__ __launch_bounds__(256) void k5_down(
    const ushort_t* __restrict__ h, const ushort_t* __restrict__ wdn,
    const int* __restrict__ hdr, const int* __restrict__ perm,
    const float* __restrict__ wts, ushort_t* __restrict__ dwn)
{
  if ((int)blockIdx.y >= hdr[H_NWORK]) return;
  int wl = hdr[H_WL + blockIdx.y];
  int e = wl >> 16, tile = wl & 0xffff;
  int gs = hdr[H_OFFS + e];
  int row0 = gs + (tile << 7);
  int nrows = hdr[H_OFFS + e + 1] - row0; if (nrows > 128) nrows = 128;
  int n0 = blockIdx.x << 7;   // out-col base (0..1023 step 128)

  __shared__ __align__(16) ushort_t As[4096];
  __shared__ __align__(16) ushort_t Bs[4096];
  __shared__ int rowslot[128];
  __shared__ float roww[128];

  int t = threadIdx.x;
  if (t < 128) {
    int sl = (t < nrows) ? perm[row0 + t] : -1;
    rowslot[t] = sl;
    roww[t] = (sl >= 0) ? wts[sl] : 0.f;
  }

  int lane = t & 63, wave = t >> 6;
  int r16 = lane >> 2, seg = lane & 3;
  int rowA0 = wave * 16 + r16;
  int rowA1 = 64 + rowA0;

  int sl0 = perm[row0 + (rowA0 < nrows ? rowA0 : 0)];
  int sl1 = perm[row0 + (rowA1 < nrows ? rowA1 : 0)];
  const ushort_t* ap0 = h + (size_t)sl0 * HID + seg * 8;
  const ushort_t* ap1 = h + (size_t)sl1 * HID + seg * 8;
  const ushort_t* wbase = wdn + (size_t)e * DIM * HID;
  const ushort_t* bp0 = wbase + (size_t)(n0 + rowA0) * HID + seg * 8;
  const ushort_t* bp1 = wbase + (size_t)(n0 + rowA1) * HID + seg * 8;

  ushort_t* lA0 = As + wave * 512;
  ushort_t* lA1 = As + 2048 + wave * 512;
  ushort_t* lB0 = Bs + wave * 512;
  ushort_t* lB1 = Bs + 2048 + wave * 512;

  floatx4 acc[16];
  #pragma unroll
  for (int i = 0; i < 16; i++) acc[i] = (floatx4){0.f, 0.f, 0.f, 0.f};

  int quad = lane >> 4, l15 = lane & 15;
  int aoff0 = ((wave * 32      + l15) << 5) + (quad << 3);
  int aoff1 = ((wave * 32 + 16 + l15) << 5) + (quad << 3);

  for (int kb = 0; kb < HID / 32; ++kb) {
    gld16(ap0, lA0); gld16(ap1, lA1); gld16(bp0, lB0); gld16(bp1, lB1);
    ap0 += 32; ap1 += 32; bp0 += 32; bp1 += 32;
    __syncthreads();
    bf16x8 af0 = *(const bf16x8*)(As + aoff0);
    bf16x8 af1 = *(const bf16x8*)(As + aoff1);
    #pragma unroll
    for (int ct = 0; ct < 8; ++ct) {
      bf16x8 bfr = *(const bf16x8*)(Bs + ((ct * 16 + l15) << 5) + (quad << 3));
      acc[ct]     = __builtin_amdgcn_mfma_f32_16x16x32_bf16(af0, bfr, acc[ct],     0, 0, 0);
      acc[8 + ct] = __builtin_amdgcn_mfma_f32_16x16x32_bf16(af1, bfr, acc[8 + ct], 0, 0, 0);
    }
    __syncthreads();
  }

  #pragma unroll
  for (int rt = 0; rt < 2; ++rt)
  #pragma unroll
  for (int ct = 0; ct < 8; ++ct) {
    floatx4 d = acc[rt * 8 + ct];
    #pragma unroll
    for (int j = 0; j < 4; ++j) {
      int r = wave * 32 + rt * 16 + quad * 4 + j;
      int slot = rowslot[r];
      if (slot >= 0)
        dwn[(size_t)slot * DIM + n0 + ct * 16 + l15] = f2bf(d[j] * roww[r]);
    }
  }
}

// out = x + dwn[2t] + dwn[2t+1]  (fp32 out, bf16 dwn)
__global__ __launch_bounds__(256) void k6_combine(
    const float* __restrict__ x, const ushort_t* __restrict__ dwn,
    float* __restrict__ out)
{
  int token = blockIdx.x, t = threadIdx.x;
  float4 xa = ((const float4*)(x + (size_t)token * DIM))[t];
  ushort4 a = ((const ushort4*)(dwn + (size_t)(2 * token)     * DIM))[t];
  ushort4 b = ((const ushort4*)(dwn + (size_t)(2 * token + 1) * DIM))[t];
  union { unsigned int i; float f; } c0, c1, c2, c3, d0, d1, d2, d3;
  c0.i = (u32)a.x << 16; c1.i = (u32)a.y << 16; c2.i = (u32)a.z << 16; c3.i = (u32)a.w << 16;
  d0.i = (u32)b.x << 16; d1.i = (u32)b.y << 16; d2.i = (u32)b.z << 16; d3.i = (u32)b.w << 16;
  float4 o;
  o.x = xa.x + c0.f + d0.f;
  o.y = xa.y + c1.f + d1.f;
  o.z = xa.z + c2.f + d2.f;
  o.w = xa.w + c3.f + d3.f;
  ((float4*)(out + (size_t)token * DIM))[t] = o;
}

extern "C" void kernel_launch(void* const* d_in, const int* in_sizes, int n_in,
                              void* d_out, int out_size, void* d_ws, size_t ws_size,
                              hipStream_t stream)
{
  const float* x   = (const float*)d_in[0];
  const float* sc  = (const float*)d_in[1];
  const float* wr  = (const float*)d_in[2];
  const float* wup = (const float*)d_in[3];
  const float* wdn = (const float*)d_in[4];
  float* out = (float*)d_out;

  char* ws = (char*)d_ws;
  int*      hdr  = (int*)ws;                          // 16 KB
  int*      ids  = (int*)(ws + 16384);                // [NSLOT]
  float*    wts  = (float*)(ws + 147456);             // [NSLOT]
  int*      perm = (int*)(ws + 278528);               // [NSLOT]
  ushort_t* xn   = (ushort_t*)(ws + 409600);          // 32 MB  [dead after k4]
  ushort_t* wupb = (ushort_t*)(ws + 33964032ull);     // 64 MB  [dead after k4]
  ushort_t* h    = (ushort_t*)(ws + 101072896ull);    // 128 MB
  ushort_t* wdnb = (ushort_t*)(ws + 67518464ull);     // 32 MB, upper half of wupb region
  ushort_t* dwn  = (ushort_t*)(ws + 409600);          // 64 MB, overlays xn + lower wupb
  // peak ws: 101072896 + 128MB = 235,290,624 B (~224 MiB)

  k0_init<<<1, 64, 0, stream>>>(hdr);
  kconv<<<4096, 256, 0, stream>>>(wup, wupb, NEXP * 2 * HID * DIM / 4);
  k1_norm_router<<<MTOK, 256, 0, stream>>>(x, sc, wr, xn, ids, wts, hdr);
  k2_scan<<<1, 64, 0, stream>>>(hdr);
  k3_scatter<<<NSLOT / 256, 256, 0, stream>>>(ids, hdr, perm);
  k4_up<<<dim3(32, 263), 256, 0, stream>>>(xn, wupb, hdr, perm, h);
  kconv<<<4096, 256, 0, stream>>>(wdn, wdnb, NEXP * DIM * HID / 4);
  k5_down<<<dim3(8, 263), 256, 0, stream>>>(h, wdnb, hdr, perm, wts, dwn);
  k6_combine<<<MTOK, 256, 0, stream>>>(x, dwn, out);
}